// Round 12
// baseline (109414.709 us; speedup 1.0000x reference)
//
#include <hip/hip_runtime.h>
#include <math.h>

#define BATCH 256
#define TSTEPS 256
#define DIN 128
#define HID 256
#define GATES 1024
#define NOUT 64

#define NGROUP 8
#define MB 32
#define NJB 32
#define NJ 8
#define NTHR 256

#define HS_OFF 0ull
#define HS_SZ  ((unsigned long long)(TSTEPS+1)*BATCH*HID)
#define BMIX_OFF HS_SZ
#define COEF_OFF (BMIX_OFF + (unsigned long long)TSTEPS*GATES)
#define FLAG_OFF (COEF_OFF + 2ull*TSTEPS)

// ---------------- prep: softmax coef, premixed bias, zero h0 and flags ----------------
__global__ void prep_kernel(const float* __restrict__ alpha,
                            const float* __restrict__ bvec,
                            float* __restrict__ wsf) {
  unsigned idx = blockIdx.x * blockDim.x + threadIdx.x;
  if (idx < (unsigned)(TSTEPS * GATES)) {
    int t = idx >> 10, col = idx & (GATES - 1);
    float a0 = alpha[2 * t], a1 = alpha[2 * t + 1];
    float m = fmaxf(a0, a1);
    float e0 = expf(a0 - m), e1 = expf(a1 - m);
    float inv = 1.f / (e0 + e1);
    wsf[BMIX_OFF + idx] = (e0 * inv) * bvec[col] + (e1 * inv) * bvec[GATES + col];
  }
  if (idx < (unsigned)(BATCH * HID)) wsf[HS_OFF + idx] = 0.f;
  if (idx < (unsigned)(2 * TSTEPS)) {
    int t = idx >> 1;
    float a0 = alpha[2 * t], a1 = alpha[2 * t + 1];
    float m = fmaxf(a0, a1);
    float e0 = expf(a0 - m), e1 = expf(a1 - m);
    float inv = 1.f / (e0 + e1);
    wsf[COEF_OFF + idx] = ((idx & 1) ? e1 : e0) * inv;
  }
  if (idx < (unsigned)(TSTEPS * NGROUP * NJB)) {
    ((unsigned*)(wsf + FLAG_OFF))[idx] = 0u;
  }
}

// ---------------- cooperative recurrent kernel ----------------
// 256 blocks = 8 batch-groups (32 rows) x 32 j-blocks (8 hidden units).
// Cross-block h/flag exchange via SYSTEM-scope RELAXED atomics served at the LLC
// (no fences, no L2 maintenance -> L2-cached data stays resident). Raw weights are
// t-invariant: each thread holds its 96 raw weight values in REGISTERS (static
// indexing only -- r9's 55ms regression was a runtime-indexed array spilling to
// scratch: 125GB HBM traffic). Premix per step = 96 FMA -> LDS. 3 barriers/step.
__global__ void __launch_bounds__(NTHR, 1) lstm_coop(const float* __restrict__ x,
                                                     const float* __restrict__ Wih,
                                                     const float* __restrict__ Whh,
                                                     float* __restrict__ wsf) {
  __shared__ float4 s_wmix[12][32 * NJ];    // all 12 premixed chunks [cc][k][j], 48KB
  __shared__ float s_h[MB][HID + 4];        // 32 x 260 (pad 4: conflict-free row reads)
  __shared__ float s_x[MB][DIN + 4];        // 32 x 132

  const int tid = threadIdx.x;
  const int bid = blockIdx.x;
  const int grp = bid & (NGROUP - 1);
  const int jb  = bid >> 3;
  const int b0  = grp * MB;
  const int j0  = jb * NJ;
  const int bloc = tid >> 3;   // 0..31 : batch row (also premix k_local)
  const int jj   = tid & 7;    // 0..7  : hidden unit within slice
  const int jcol = j0 + jj;

  float* hs = wsf + HS_OFF;
  const float* bmix = wsf + BMIX_OFF;
  const float* coef = wsf + COEF_OFF;
  unsigned* flags = (unsigned*)(wsf + FLAG_OFF);

  // ---- load raw weights into registers ONCE (t-invariant; static indices only) ----
  float rw0[12][4], rw1[12][4];
  #pragma unroll
  for (int cc = 0; cc < 12; ++cc) {
    const float* p0 = (cc < 8) ? (Whh + (size_t)(cc * 32 + bloc) * GATES + jcol)
                               : (Wih + (size_t)((cc - 8) * 32 + bloc) * GATES + jcol);
    const float* p1 = p0 + ((cc < 8) ? HID * GATES : DIN * GATES);
    #pragma unroll
    for (int u = 0; u < 4; ++u) { rw0[cc][u] = p0[u * 256]; rw1[cc][u] = p1[u * 256]; }
  }

  float c_state = 0.f;

  for (int t = 0; t < TSTEPS; ++t) {
    // ---- premix all 12 chunks from registers into LDS (peer-independent) ----
    const float c0 = coef[2 * t], c1 = coef[2 * t + 1];
    #pragma unroll
    for (int cc = 0; cc < 12; ++cc) {
      float4 wv;
      wv.x = c0 * rw0[cc][0] + c1 * rw1[cc][0];
      wv.y = c0 * rw0[cc][1] + c1 * rw1[cc][1];
      wv.z = c0 * rw0[cc][2] + c1 * rw1[cc][2];
      wv.w = c0 * rw0[cc][3] + c1 * rw1[cc][3];
      s_wmix[cc][bloc * NJ + jj] = wv;
    }
    // ---- x tile fill (peer-independent) ----
    {
      const float* xr = x + ((size_t)(b0 + bloc) * TSTEPS + t) * DIN + jj * 16;
      float* xd = &s_x[bloc][jj * 16];
      #pragma unroll
      for (int i = 0; i < 4; ++i)
        *reinterpret_cast<float4*>(xd + i * 4) = *reinterpret_cast<const float4*>(xr + i * 4);
    }
    // ---- wait for previous step's h from all 32 j-blocks of this group ----
    if (t > 0) {
      if (tid < 64) {
        unsigned* fl = flags + (size_t)(t - 1) * (NGROUP * NJB) + grp * NJB;
        for (;;) {
          unsigned v = (tid < NJB)
            ? __hip_atomic_load(fl + tid, __ATOMIC_RELAXED, __HIP_MEMORY_SCOPE_SYSTEM)
            : 1u;
          if (__all(v != 0u)) break;
          __builtin_amdgcn_s_sleep(1);
        }
      }
      __syncthreads();
    }
    // ---- h tile fill: system-scope dword loads (LLC), conflict-free pattern ----
    {
      const int w = tid >> 6, lane = tid & 63;
      float* hsrc = hs + (size_t)t * BATCH * HID + (size_t)b0 * HID;
      #pragma unroll
      for (int r8 = 0; r8 < 8; ++r8) {
        int row = w * 8 + r8;
        #pragma unroll
        for (int m = 0; m < 4; ++m) {
          int col = lane + m * 64;
          s_h[row][col] = __hip_atomic_load(hsrc + (size_t)row * HID + col,
                                            __ATOMIC_RELAXED, __HIP_MEMORY_SCOPE_SYSTEM);
        }
      }
    }
    __syncthreads();   // premix + x + h all visible block-wide

    // ---- gate dots: 12 chunks, no intra-loop barriers ----
    float acc0 = 0.f, acc1 = 0.f, acc2 = 0.f, acc3 = 0.f;
    const float* hrow = &s_h[bloc][0];
    const float* xrow = &s_x[bloc][0];
    #pragma unroll
    for (int cc = 0; cc < 12; ++cc) {
      const float4* wm = s_wmix[cc];
      const float* hb = (cc < 8) ? (hrow + cc * 32) : (xrow + (cc - 8) * 32);
      #pragma unroll
      for (int k4 = 0; k4 < 8; ++k4) {
        float4 hv = *reinterpret_cast<const float4*>(hb + k4 * 4);
        float4 w;
        w = wm[(k4 * 4 + 0) * NJ + jj];
        acc0 += hv.x * w.x; acc1 += hv.x * w.y; acc2 += hv.x * w.z; acc3 += hv.x * w.w;
        w = wm[(k4 * 4 + 1) * NJ + jj];
        acc0 += hv.y * w.x; acc1 += hv.y * w.y; acc2 += hv.y * w.z; acc3 += hv.y * w.w;
        w = wm[(k4 * 4 + 2) * NJ + jj];
        acc0 += hv.z * w.x; acc1 += hv.z * w.y; acc2 += hv.z * w.z; acc3 += hv.z * w.w;
        w = wm[(k4 * 4 + 3) * NJ + jj];
        acc0 += hv.w * w.x; acc1 += hv.w * w.y; acc2 += hv.w * w.z; acc3 += hv.w * w.w;
      }
    }

    // ---- LSTM cell ----
    const float* bm = bmix + (size_t)t * GATES + jcol;
    float pi = acc0 + bm[0];
    float pf = acc1 + bm[256];
    float pg = acc2 + bm[512];
    float po = acc3 + bm[768];
    float iv = 1.f / (1.f + expf(-pi));
    float fv = 1.f / (1.f + expf(-pf));
    float gv = tanhf(pg);
    float ov = 1.f / (1.f + expf(-po));
    c_state = fv * c_state + iv * gv;
    float hv = ov * tanhf(c_state);
    // publish h at the device coherence point
    __hip_atomic_store(&hs[(size_t)(t + 1) * BATCH * HID + (size_t)(b0 + bloc) * HID + jcol],
                       hv, __ATOMIC_RELAXED, __HIP_MEMORY_SCOPE_SYSTEM);
    __builtin_amdgcn_s_waitcnt(0);   // own h stores acked before barrier
    __syncthreads();                 // ...all threads' stores acked
    if (tid == 0)
      __hip_atomic_store(&flags[(size_t)t * (NGROUP * NJB) + grp * NJB + jb], 1u,
                         __ATOMIC_RELAXED, __HIP_MEMORY_SCOPE_SYSTEM);
  }
}

// ---------------- output projection: out[b,t,:] = hs[t+1,b,:] @ W_out + b_out ----------------
__global__ void __launch_bounds__(256) out_kernel(const float* __restrict__ wsf,
                                                  const float* __restrict__ Wout,
                                                  const float* __restrict__ bout,
                                                  float* __restrict__ outp) {
  __shared__ float s_ht[HID][MB];
  __shared__ float s_wo[HID][32];
  const int tid = threadIdx.x;
  const int rb = blockIdx.x;
  const int cb = blockIdx.y;
  const float* hs1 = wsf + HS_OFF + (size_t)BATCH * HID;
  const int ri0 = rb * MB;
  {
    const int r = tid & 31, kq = tid >> 5;
    const float* hr = hs1 + (size_t)(ri0 + r) * HID + kq * 32;
    #pragma unroll
    for (int i = 0; i < 8; ++i) {
      float4 v = *reinterpret_cast<const float4*>(hr + i * 4);
      int k = kq * 32 + i * 4;
      s_ht[k + 0][r] = v.x; s_ht[k + 1][r] = v.y; s_ht[k + 2][r] = v.z; s_ht[k + 3][r] = v.w;
    }
  }
  {
    #pragma unroll
    for (int i = 0; i < 32; ++i) {
      int e = i * 256 + tid;
      int k = e >> 5, o = e & 31;
      s_wo[k][o] = Wout[k * NOUT + cb * 32 + o];
    }
  }
  __syncthreads();
  const int row = tid >> 3, oq = tid & 7;
  float4 acc = *reinterpret_cast<const float4*>(bout + cb * 32 + oq * 4);
  #pragma unroll 4
  for (int k = 0; k < HID; ++k) {
    float hv = s_ht[k][row];
    float4 w = *reinterpret_cast<const float4*>(&s_wo[k][oq * 4]);
    acc.x += hv * w.x; acc.y += hv * w.y; acc.z += hv * w.z; acc.w += hv * w.w;
  }
  const int ri = ri0 + row;
  const int tt = ri >> 8, bb = ri & 255;
  *reinterpret_cast<float4*>(outp + ((size_t)bb * TSTEPS + tt) * NOUT + cb * 32 + oq * 4) = acc;
}

extern "C" void kernel_launch(void* const* d_in, const int* in_sizes, int n_in,
                              void* d_out, int out_size, void* d_ws, size_t ws_size,
                              hipStream_t stream) {
  const float* x     = (const float*)d_in[0];
  const float* Wih   = (const float*)d_in[1];
  const float* Whh   = (const float*)d_in[2];
  const float* bvec  = (const float*)d_in[3];
  const float* alpha = (const float*)d_in[4];
  const float* Wout  = (const float*)d_in[5];
  const float* bout  = (const float*)d_in[6];
  float* outp = (float*)d_out;
  float* wsf  = (float*)d_ws;

  prep_kernel<<<dim3((TSTEPS * GATES + 255) / 256), dim3(256), 0, stream>>>(alpha, bvec, wsf);

  void* args[] = { (void*)&x, (void*)&Wih, (void*)&Whh, (void*)&wsf };
  hipError_t err = hipLaunchCooperativeKernel((void*)lstm_coop, dim3(NGROUP * NJB), dim3(NTHR),
                                              args, 0, stream);
  if (err != hipSuccess) {
    // fallback: 98KB LDS -> 1 block/CU, 256 blocks on 256 CUs co-resident
    lstm_coop<<<dim3(NGROUP * NJB), dim3(NTHR), 0, stream>>>(x, Wih, Whh, wsf);
  }

  out_kernel<<<dim3((BATCH * TSTEPS) / MB, 2), dim3(256), 0, stream>>>(wsf, Wout, bout, outp);
}

// Round 13
// 109274.536 us; speedup vs baseline: 1.0013x; 1.0013x over previous
//
#include <hip/hip_runtime.h>
#include <math.h>

#define BATCH 256
#define TSTEPS 256
#define DIN 128
#define HID 256
#define GATES 1024
#define NOUT 64

#define NGROUP 8
#define MB 32
#define NJB 32
#define NJ 8
#define NTHR 256

#define HS_OFF 0ull
#define HS_SZ  ((unsigned long long)(TSTEPS+1)*BATCH*HID)
#define BMIX_OFF HS_SZ
#define COEF_OFF (BMIX_OFF + (unsigned long long)TSTEPS*GATES)
#define FLAG_OFF (COEF_OFF + 2ull*TSTEPS)

// ---------------- prep: softmax coef, premixed bias, zero h0 and flags ----------------
__global__ void prep_kernel(const float* __restrict__ alpha,
                            const float* __restrict__ bvec,
                            float* __restrict__ wsf) {
  unsigned idx = blockIdx.x * blockDim.x + threadIdx.x;
  if (idx < (unsigned)(TSTEPS * GATES)) {
    int t = idx >> 10, col = idx & (GATES - 1);
    float a0 = alpha[2 * t], a1 = alpha[2 * t + 1];
    float m = fmaxf(a0, a1);
    float e0 = expf(a0 - m), e1 = expf(a1 - m);
    float inv = 1.f / (e0 + e1);
    wsf[BMIX_OFF + idx] = (e0 * inv) * bvec[col] + (e1 * inv) * bvec[GATES + col];
  }
  if (idx < (unsigned)(BATCH * HID)) wsf[HS_OFF + idx] = 0.f;
  if (idx < (unsigned)(2 * TSTEPS)) {
    int t = idx >> 1;
    float a0 = alpha[2 * t], a1 = alpha[2 * t + 1];
    float m = fmaxf(a0, a1);
    float e0 = expf(a0 - m), e1 = expf(a1 - m);
    float inv = 1.f / (e0 + e1);
    wsf[COEF_OFF + idx] = ((idx & 1) ? e1 : e0) * inv;
  }
  if (idx < (unsigned)(TSTEPS * NGROUP * NJB)) {
    ((unsigned*)(wsf + FLAG_OFF))[idx] = 0u;
  }
}

// ---------------- cooperative recurrent kernel ----------------
// 256 blocks = 8 batch-groups (32 rows) x 32 j-blocks (8 hidden units).
// LESSONS ENCODED HERE:
//  r7  (fenced agent-scope exchange): correct, 12.9ms -- ~47us/step lost to per-step
//      L2 writeback/invalidate serialization; but premix-from-L2 ran at 108 VGPR, no spill.
//  r9/r12 (register-resident weights): VGPR capped at 256 -> in-loop scratch spill,
//      79-94 GB/dispatch of spill WRITES, 55-127ms. Weights CANNOT live in registers.
// => r13: r7's premix-from-L2 (streaming, 8 floats live at a time, weights stay
//    L2-resident: 3.1MB/XCD) + r9/r12's validated fence-free SYSTEM-scope relaxed
//    atomic h/flag exchange. 3 barriers/step, no persistent register arrays.
__global__ void __launch_bounds__(NTHR, 1) lstm_coop(const float* __restrict__ x,
                                                     const float* __restrict__ Wih,
                                                     const float* __restrict__ Whh,
                                                     float* __restrict__ wsf) {
  __shared__ float4 s_wmix[12][32 * NJ];    // all 12 premixed chunks [cc][k][j], 48KB
  __shared__ float s_h[MB][HID + 4];        // 32 x 260
  __shared__ float s_x[MB][DIN + 4];        // 32 x 132

  const int tid = threadIdx.x;
  const int bid = blockIdx.x;
  const int grp = bid & (NGROUP - 1);
  const int jb  = bid >> 3;
  const int b0  = grp * MB;
  const int j0  = jb * NJ;
  const int bloc = tid >> 3;   // 0..31 : batch row (also premix k_local)
  const int jj   = tid & 7;    // 0..7  : hidden unit within slice
  const int jcol = j0 + jj;

  float* hs = wsf + HS_OFF;
  const float* bmix = wsf + BMIX_OFF;
  const float* coef = wsf + COEF_OFF;
  unsigned* flags = (unsigned*)(wsf + FLAG_OFF);

  // per-thread premix source bases (weights are read L2->reg->LDS each step;
  // per-XCD slice = 3.1MB, stays L2-resident across all 256 steps)
  const float* whhT = Whh + bloc * GATES + jcol;
  const float* wihT = Wih + bloc * GATES + jcol;

  float c_state = 0.f;

  for (int t = 0; t < TSTEPS; ++t) {
    const float c0 = coef[2 * t], c1 = coef[2 * t + 1];
    // ---- premix: stream each chunk L2 -> 8 regs -> fma -> LDS (nothing persists) ----
    #pragma unroll
    for (int cc = 0; cc < 12; ++cc) {
      const float* p0 = (cc < 8) ? (whhT + cc * 32 * GATES) : (wihT + (cc - 8) * 32 * GATES);
      const float* p1 = p0 + ((cc < 8) ? HID * GATES : DIN * GATES);
      float4 wv;
      wv.x = c0 * p0[0]   + c1 * p1[0];
      wv.y = c0 * p0[256] + c1 * p1[256];
      wv.z = c0 * p0[512] + c1 * p1[512];
      wv.w = c0 * p0[768] + c1 * p1[768];
      s_wmix[cc][bloc * NJ + jj] = wv;
    }
    // ---- x tile fill (peer-independent, normal cached loads) ----
    {
      const float* xr = x + ((size_t)(b0 + bloc) * TSTEPS + t) * DIN + jj * 16;
      float* xd = &s_x[bloc][jj * 16];
      #pragma unroll
      for (int i = 0; i < 4; ++i)
        *reinterpret_cast<float4*>(xd + i * 4) = *reinterpret_cast<const float4*>(xr + i * 4);
    }
    // ---- wait for previous step's h from all 32 j-blocks of this group ----
    if (t > 0) {
      if (tid < 64) {
        unsigned* fl = flags + (size_t)(t - 1) * (NGROUP * NJB) + grp * NJB;
        for (;;) {
          unsigned v = (tid < NJB)
            ? __hip_atomic_load(fl + tid, __ATOMIC_RELAXED, __HIP_MEMORY_SCOPE_SYSTEM)
            : 1u;
          if (__all(v != 0u)) break;
          __builtin_amdgcn_s_sleep(4);   // wider sleep: cut poll traffic ~3x
        }
      }
      __syncthreads();
    }
    // ---- h tile fill: relaxed system dword loads, coalesced 256B/wave-inst ----
    {
      const int w = tid >> 6, lane = tid & 63;
      float* hsrc = hs + (size_t)t * BATCH * HID + (size_t)b0 * HID;
      #pragma unroll
      for (int r8 = 0; r8 < 8; ++r8) {
        int row = w * 8 + r8;
        #pragma unroll
        for (int m = 0; m < 4; ++m) {
          int col = lane + m * 64;
          s_h[row][col] = __hip_atomic_load(hsrc + (size_t)row * HID + col,
                                            __ATOMIC_RELAXED, __HIP_MEMORY_SCOPE_SYSTEM);
        }
      }
    }
    __syncthreads();   // premix + x + h all visible block-wide

    // ---- gate dots: 12 chunks, no intra-loop barriers ----
    float acc0 = 0.f, acc1 = 0.f, acc2 = 0.f, acc3 = 0.f;
    const float* hrow = &s_h[bloc][0];
    const float* xrow = &s_x[bloc][0];
    #pragma unroll
    for (int cc = 0; cc < 12; ++cc) {
      const float4* wm = s_wmix[cc];
      const float* hb = (cc < 8) ? (hrow + cc * 32) : (xrow + (cc - 8) * 32);
      #pragma unroll
      for (int k4 = 0; k4 < 8; ++k4) {
        float4 hv = *reinterpret_cast<const float4*>(hb + k4 * 4);
        float4 w;
        w = wm[(k4 * 4 + 0) * NJ + jj];
        acc0 += hv.x * w.x; acc1 += hv.x * w.y; acc2 += hv.x * w.z; acc3 += hv.x * w.w;
        w = wm[(k4 * 4 + 1) * NJ + jj];
        acc0 += hv.y * w.x; acc1 += hv.y * w.y; acc2 += hv.y * w.z; acc3 += hv.y * w.w;
        w = wm[(k4 * 4 + 2) * NJ + jj];
        acc0 += hv.z * w.x; acc1 += hv.z * w.y; acc2 += hv.z * w.z; acc3 += hv.z * w.w;
        w = wm[(k4 * 4 + 3) * NJ + jj];
        acc0 += hv.w * w.x; acc1 += hv.w * w.y; acc2 += hv.w * w.z; acc3 += hv.w * w.w;
      }
    }

    // ---- LSTM cell ----
    const float* bm = bmix + (size_t)t * GATES + jcol;
    float pi = acc0 + bm[0];
    float pf = acc1 + bm[256];
    float pg = acc2 + bm[512];
    float po = acc3 + bm[768];
    float iv = 1.f / (1.f + expf(-pi));
    float fv = 1.f / (1.f + expf(-pf));
    float gv = tanhf(pg);
    float ov = 1.f / (1.f + expf(-po));
    c_state = fv * c_state + iv * gv;
    float hv = ov * tanhf(c_state);
    // publish h at the device coherence point
    __hip_atomic_store(&hs[(size_t)(t + 1) * BATCH * HID + (size_t)(b0 + bloc) * HID + jcol],
                       hv, __ATOMIC_RELAXED, __HIP_MEMORY_SCOPE_SYSTEM);
    __builtin_amdgcn_s_waitcnt(0);   // own h store acked before barrier
    __syncthreads();                 // ...all threads' stores acked
    if (tid == 0)
      __hip_atomic_store(&flags[(size_t)t * (NGROUP * NJB) + grp * NJB + jb], 1u,
                         __ATOMIC_RELAXED, __HIP_MEMORY_SCOPE_SYSTEM);
  }
}

// ---------------- output projection: out[b,t,:] = hs[t+1,b,:] @ W_out + b_out ----------------
__global__ void __launch_bounds__(256) out_kernel(const float* __restrict__ wsf,
                                                  const float* __restrict__ Wout,
                                                  const float* __restrict__ bout,
                                                  float* __restrict__ outp) {
  __shared__ float s_ht[HID][MB];
  __shared__ float s_wo[HID][32];
  const int tid = threadIdx.x;
  const int rb = blockIdx.x;
  const int cb = blockIdx.y;
  const float* hs1 = wsf + HS_OFF + (size_t)BATCH * HID;
  const int ri0 = rb * MB;
  {
    const int r = tid & 31, kq = tid >> 5;
    const float* hr = hs1 + (size_t)(ri0 + r) * HID + kq * 32;
    #pragma unroll
    for (int i = 0; i < 8; ++i) {
      float4 v = *reinterpret_cast<const float4*>(hr + i * 4);
      int k = kq * 32 + i * 4;
      s_ht[k + 0][r] = v.x; s_ht[k + 1][r] = v.y; s_ht[k + 2][r] = v.z; s_ht[k + 3][r] = v.w;
    }
  }
  {
    #pragma unroll
    for (int i = 0; i < 32; ++i) {
      int e = i * 256 + tid;
      int k = e >> 5, o = e & 31;
      s_wo[k][o] = Wout[k * NOUT + cb * 32 + o];
    }
  }
  __syncthreads();
  const int row = tid >> 3, oq = tid & 7;
  float4 acc = *reinterpret_cast<const float4*>(bout + cb * 32 + oq * 4);
  #pragma unroll 4
  for (int k = 0; k < HID; ++k) {
    float hv = s_ht[k][row];
    float4 w = *reinterpret_cast<const float4*>(&s_wo[k][oq * 4]);
    acc.x += hv * w.x; acc.y += hv * w.y; acc.z += hv * w.z; acc.w += hv * w.w;
  }
  const int ri = ri0 + row;
  const int tt = ri >> 8, bb = ri & 255;
  *reinterpret_cast<float4*>(outp + ((size_t)bb * TSTEPS + tt) * NOUT + cb * 32 + oq * 4) = acc;
}

extern "C" void kernel_launch(void* const* d_in, const int* in_sizes, int n_in,
                              void* d_out, int out_size, void* d_ws, size_t ws_size,
                              hipStream_t stream) {
  const float* x     = (const float*)d_in[0];
  const float* Wih   = (const float*)d_in[1];
  const float* Whh   = (const float*)d_in[2];
  const float* bvec  = (const float*)d_in[3];
  const float* alpha = (const float*)d_in[4];
  const float* Wout  = (const float*)d_in[5];
  const float* bout  = (const float*)d_in[6];
  float* outp = (float*)d_out;
  float* wsf  = (float*)d_ws;

  prep_kernel<<<dim3((TSTEPS * GATES + 255) / 256), dim3(256), 0, stream>>>(alpha, bvec, wsf);

  void* args[] = { (void*)&x, (void*)&Wih, (void*)&Whh, (void*)&wsf };
  hipError_t err = hipLaunchCooperativeKernel((void*)lstm_coop, dim3(NGROUP * NJB), dim3(NTHR),
                                              args, 0, stream);
  if (err != hipSuccess) {
    // fallback: 98KB LDS -> 1 block/CU, 256 blocks on 256 CUs co-resident
    lstm_coop<<<dim3(NGROUP * NJB), dim3(NTHR), 0, stream>>>(x, Wih, Whh, wsf);
  }

  out_kernel<<<dim3((BATCH * TSTEPS) / MB, 2), dim3(256), 0, stream>>>(wsf, Wout, bout, outp);
}

// Round 14
// 108186.926 us; speedup vs baseline: 1.0113x; 1.0101x over previous
//
#include <hip/hip_runtime.h>
#include <math.h>
#include <stdint.h>

#define BATCH 256
#define TSTEPS 256
#define DIN 128
#define HID 256
#define GATES 1024
#define NOUT 64

#define NGROUP 8
#define MB 32
#define NJB 32
#define NJ 8
#define NTHR 256

#define HS_OFF 0ull
#define HS_SZ  ((unsigned long long)(TSTEPS+1)*BATCH*HID)
#define BMIX_OFF HS_SZ
#define COEF_OFF (BMIX_OFF + (unsigned long long)TSTEPS*GATES)
#define FLAG_OFF (COEF_OFF + 2ull*TSTEPS)

// ---------------- prep: softmax coef, premixed bias, zero h0 and flags ----------------
__global__ void prep_kernel(const float* __restrict__ alpha,
                            const float* __restrict__ bvec,
                            float* __restrict__ wsf) {
  unsigned idx = blockIdx.x * blockDim.x + threadIdx.x;
  if (idx < (unsigned)(TSTEPS * GATES)) {
    int t = idx >> 10, col = idx & (GATES - 1);
    float a0 = alpha[2 * t], a1 = alpha[2 * t + 1];
    float m = fmaxf(a0, a1);
    float e0 = expf(a0 - m), e1 = expf(a1 - m);
    float inv = 1.f / (e0 + e1);
    wsf[BMIX_OFF + idx] = (e0 * inv) * bvec[col] + (e1 * inv) * bvec[GATES + col];
  }
  if (idx < (unsigned)(BATCH * HID)) wsf[HS_OFF + idx] = 0.f;
  if (idx < (unsigned)(2 * TSTEPS)) {
    int t = idx >> 1;
    float a0 = alpha[2 * t], a1 = alpha[2 * t + 1];
    float m = fmaxf(a0, a1);
    float e0 = expf(a0 - m), e1 = expf(a1 - m);
    float inv = 1.f / (e0 + e1);
    wsf[COEF_OFF + idx] = ((idx & 1) ? e1 : e0) * inv;
  }
  if (idx < (unsigned)(TSTEPS * NGROUP * NJB)) {
    ((unsigned*)(wsf + FLAG_OFF))[idx] = 0u;
  }
}

// ---------------- cooperative recurrent kernel ----------------
// 256 blocks = 8 batch-groups (32 rows) x 32 j-blocks (8 hidden units).
// HISTORY: r7 fenced exchange = 12.9ms (fence serialization). r9/r12 register-
// resident weights = VGPR cap + spill thrash (79-94GB scratch writes, 55-127ms).
// r13 "streaming premix" produced BIT-IDENTICAL counters to r12: LICM hoisted the
// t-invariant weight loads back into 96 live registers -> same binary.
// => r14: premix loads made UN-HOISTABLE two ways: (1) asm-laundered base pointers
//    per t-iteration (compiler must assume they changed), (2) rolled loops
//    (#pragma unroll 1) so load addresses depend on a runtime induction var.
//    Weights stream L2->reg->LDS each step (8 floats live at a time).
__global__ void __launch_bounds__(NTHR, 1) lstm_coop(const float* __restrict__ x,
                                                     const float* __restrict__ Wih,
                                                     const float* __restrict__ Whh,
                                                     float* __restrict__ wsf) {
  __shared__ float4 s_wmix[12][32 * NJ];    // all 12 premixed chunks [cc][k][j], 48KB
  __shared__ float s_h[MB][HID + 4];        // 32 x 260
  __shared__ float s_x[MB][DIN + 4];        // 32 x 132

  const int tid = threadIdx.x;
  const int bid = blockIdx.x;
  const int grp = bid & (NGROUP - 1);
  const int jb  = bid >> 3;
  const int b0  = grp * MB;
  const int j0  = jb * NJ;
  const int bloc = tid >> 3;   // 0..31 : batch row (also premix k_local)
  const int jj   = tid & 7;    // 0..7  : hidden unit within slice
  const int jcol = j0 + jj;

  float* hs = wsf + HS_OFF;
  const float* bmix = wsf + BMIX_OFF;
  const float* coef = wsf + COEF_OFF;
  unsigned* flags = (unsigned*)(wsf + FLAG_OFF);

  float c_state = 0.f;

  for (int t = 0; t < TSTEPS; ++t) {
    const float c0 = coef[2 * t], c1 = coef[2 * t + 1];

    // ---- premix: stream L2 -> 8 regs -> fma -> LDS. Loads are LICM-proof:
    // base addresses laundered through asm each iteration + rolled loops.
    uintptr_t wa = (uintptr_t)(Whh + (size_t)bloc * GATES + jcol);
    uintptr_t xa = (uintptr_t)(Wih + (size_t)bloc * GATES + jcol);
    asm volatile("" : "+v"(wa), "+v"(xa));
    const float* whh_p = (const float*)wa;
    const float* wih_p = (const float*)xa;
    #pragma unroll 1
    for (int cc = 0; cc < 8; ++cc) {
      const float* p0 = whh_p + (size_t)cc * 32 * GATES;
      const float* p1 = p0 + (size_t)HID * GATES;
      float4 wv;
      wv.x = c0 * p0[0]   + c1 * p1[0];
      wv.y = c0 * p0[256] + c1 * p1[256];
      wv.z = c0 * p0[512] + c1 * p1[512];
      wv.w = c0 * p0[768] + c1 * p1[768];
      s_wmix[cc][bloc * NJ + jj] = wv;
    }
    #pragma unroll 1
    for (int cc = 0; cc < 4; ++cc) {
      const float* p0 = wih_p + (size_t)cc * 32 * GATES;
      const float* p1 = p0 + (size_t)DIN * GATES;
      float4 wv;
      wv.x = c0 * p0[0]   + c1 * p1[0];
      wv.y = c0 * p0[256] + c1 * p1[256];
      wv.z = c0 * p0[512] + c1 * p1[512];
      wv.w = c0 * p0[768] + c1 * p1[768];
      s_wmix[8 + cc][bloc * NJ + jj] = wv;
    }
    // ---- x tile fill (peer-independent, normal cached loads) ----
    {
      const float* xr = x + ((size_t)(b0 + bloc) * TSTEPS + t) * DIN + jj * 16;
      float* xd = &s_x[bloc][jj * 16];
      #pragma unroll
      for (int i = 0; i < 4; ++i)
        *reinterpret_cast<float4*>(xd + i * 4) = *reinterpret_cast<const float4*>(xr + i * 4);
    }
    // ---- wait for previous step's h from all 32 j-blocks of this group ----
    if (t > 0) {
      if (tid < 64) {
        unsigned* fl = flags + (size_t)(t - 1) * (NGROUP * NJB) + grp * NJB;
        for (;;) {
          unsigned v = (tid < NJB)
            ? __hip_atomic_load(fl + tid, __ATOMIC_RELAXED, __HIP_MEMORY_SCOPE_SYSTEM)
            : 1u;
          if (__all(v != 0u)) break;
          __builtin_amdgcn_s_sleep(4);
        }
      }
      __syncthreads();
    }
    // ---- h tile fill: relaxed system dword loads (LLC), coalesced ----
    {
      const int w = tid >> 6, lane = tid & 63;
      float* hsrc = hs + (size_t)t * BATCH * HID + (size_t)b0 * HID;
      #pragma unroll
      for (int r8 = 0; r8 < 8; ++r8) {
        int row = w * 8 + r8;
        #pragma unroll
        for (int m = 0; m < 4; ++m) {
          int col = lane + m * 64;
          s_h[row][col] = __hip_atomic_load(hsrc + (size_t)row * HID + col,
                                            __ATOMIC_RELAXED, __HIP_MEMORY_SCOPE_SYSTEM);
        }
      }
    }
    __syncthreads();   // premix + x + h all visible block-wide

    // ---- gate dots: 12 chunks, no intra-loop barriers ----
    float acc0 = 0.f, acc1 = 0.f, acc2 = 0.f, acc3 = 0.f;
    const float* hrow = &s_h[bloc][0];
    const float* xrow = &s_x[bloc][0];
    #pragma unroll
    for (int cc = 0; cc < 12; ++cc) {
      const float4* wm = s_wmix[cc];
      const float* hb = (cc < 8) ? (hrow + cc * 32) : (xrow + (cc - 8) * 32);
      #pragma unroll
      for (int k4 = 0; k4 < 8; ++k4) {
        float4 hv = *reinterpret_cast<const float4*>(hb + k4 * 4);
        float4 w;
        w = wm[(k4 * 4 + 0) * NJ + jj];
        acc0 += hv.x * w.x; acc1 += hv.x * w.y; acc2 += hv.x * w.z; acc3 += hv.x * w.w;
        w = wm[(k4 * 4 + 1) * NJ + jj];
        acc0 += hv.y * w.x; acc1 += hv.y * w.y; acc2 += hv.y * w.z; acc3 += hv.y * w.w;
        w = wm[(k4 * 4 + 2) * NJ + jj];
        acc0 += hv.z * w.x; acc1 += hv.z * w.y; acc2 += hv.z * w.z; acc3 += hv.z * w.w;
        w = wm[(k4 * 4 + 3) * NJ + jj];
        acc0 += hv.w * w.x; acc1 += hv.w * w.y; acc2 += hv.w * w.z; acc3 += hv.w * w.w;
      }
    }

    // ---- LSTM cell ----
    const float* bm = bmix + (size_t)t * GATES + jcol;
    float pi = acc0 + bm[0];
    float pf = acc1 + bm[256];
    float pg = acc2 + bm[512];
    float po = acc3 + bm[768];
    float iv = 1.f / (1.f + expf(-pi));
    float fv = 1.f / (1.f + expf(-pf));
    float gv = tanhf(pg);
    float ov = 1.f / (1.f + expf(-po));
    c_state = fv * c_state + iv * gv;
    float hv = ov * tanhf(c_state);
    // publish h at the device coherence point
    __hip_atomic_store(&hs[(size_t)(t + 1) * BATCH * HID + (size_t)(b0 + bloc) * HID + jcol],
                       hv, __ATOMIC_RELAXED, __HIP_MEMORY_SCOPE_SYSTEM);
    __builtin_amdgcn_s_waitcnt(0);   // own h store acked before barrier
    __syncthreads();                 // ...all threads' stores acked
    if (tid == 0)
      __hip_atomic_store(&flags[(size_t)t * (NGROUP * NJB) + grp * NJB + jb], 1u,
                         __ATOMIC_RELAXED, __HIP_MEMORY_SCOPE_SYSTEM);
  }
}

// ---------------- output projection: out[b,t,:] = hs[t+1,b,:] @ W_out + b_out ----------------
__global__ void __launch_bounds__(256) out_kernel(const float* __restrict__ wsf,
                                                  const float* __restrict__ Wout,
                                                  const float* __restrict__ bout,
                                                  float* __restrict__ outp) {
  __shared__ float s_ht[HID][MB];
  __shared__ float s_wo[HID][32];
  const int tid = threadIdx.x;
  const int rb = blockIdx.x;
  const int cb = blockIdx.y;
  const float* hs1 = wsf + HS_OFF + (size_t)BATCH * HID;
  const int ri0 = rb * MB;
  {
    const int r = tid & 31, kq = tid >> 5;
    const float* hr = hs1 + (size_t)(ri0 + r) * HID + kq * 32;
    #pragma unroll
    for (int i = 0; i < 8; ++i) {
      float4 v = *reinterpret_cast<const float4*>(hr + i * 4);
      int k = kq * 32 + i * 4;
      s_ht[k + 0][r] = v.x; s_ht[k + 1][r] = v.y; s_ht[k + 2][r] = v.z; s_ht[k + 3][r] = v.w;
    }
  }
  {
    #pragma unroll
    for (int i = 0; i < 32; ++i) {
      int e = i * 256 + tid;
      int k = e >> 5, o = e & 31;
      s_wo[k][o] = Wout[k * NOUT + cb * 32 + o];
    }
  }
  __syncthreads();
  const int row = tid >> 3, oq = tid & 7;
  float4 acc = *reinterpret_cast<const float4*>(bout + cb * 32 + oq * 4);
  #pragma unroll 4
  for (int k = 0; k < HID; ++k) {
    float hv = s_ht[k][row];
    float4 w = *reinterpret_cast<const float4*>(&s_wo[k][oq * 4]);
    acc.x += hv * w.x; acc.y += hv * w.y; acc.z += hv * w.z; acc.w += hv * w.w;
  }
  const int ri = ri0 + row;
  const int tt = ri >> 8, bb = ri & 255;
  *reinterpret_cast<float4*>(outp + ((size_t)bb * TSTEPS + tt) * NOUT + cb * 32 + oq * 4) = acc;
}

extern "C" void kernel_launch(void* const* d_in, const int* in_sizes, int n_in,
                              void* d_out, int out_size, void* d_ws, size_t ws_size,
                              hipStream_t stream) {
  const float* x     = (const float*)d_in[0];
  const float* Wih   = (const float*)d_in[1];
  const float* Whh   = (const float*)d_in[2];
  const float* bvec  = (const float*)d_in[3];
  const float* alpha = (const float*)d_in[4];
  const float* Wout  = (const float*)d_in[5];
  const float* bout  = (const float*)d_in[6];
  float* outp = (float*)d_out;
  float* wsf  = (float*)d_ws;

  prep_kernel<<<dim3((TSTEPS * GATES + 255) / 256), dim3(256), 0, stream>>>(alpha, bvec, wsf);

  void* args[] = { (void*)&x, (void*)&Wih, (void*)&Whh, (void*)&wsf };
  hipError_t err = hipLaunchCooperativeKernel((void*)lstm_coop, dim3(NGROUP * NJB), dim3(NTHR),
                                              args, 0, stream);
  if (err != hipSuccess) {
    // fallback: 98KB LDS -> 1 block/CU, 256 blocks on 256 CUs co-resident
    lstm_coop<<<dim3(NGROUP * NJB), dim3(NTHR), 0, stream>>>(x, Wih, Whh, wsf);
  }

  out_kernel<<<dim3((BATCH * TSTEPS) / MB, 2), dim3(256), 0, stream>>>(wsf, Wout, bout, outp);
}